// Round 14
// baseline (2751.522 us; speedup 1.0000x reference)
//
#include <hip/hip_runtime.h>

// Liquid-network scan, r14 = r13 + explicit amdgpu_waves_per_eu(2,2).
// r12/r13 showed the allocator pinning 128 VGPR (4 waves/EU target) and
// spilling ~32 regs -> 7-8 MB scratch traffic/dispatch; per-batch throughput
// STILL matched r8 even while spilling, so the cross-batch TLP gain is real
// and was being cancelled by the spill. waves_per_eu(2,2) sets the budget to
// 512-reg pool / 2 = 256 VGPR/wave (2 waves/SIMD = exactly one 512-thread
// block per CU, which the 147 KB LDS already forces). b_in folded into wave
// 0's partial (r10 trick) to shave loop-carried registers.
// Structure: TWO independent batches per block (512 thr = 2 groups x 4
// waves; grid = 64). Each group = r8's machine: register-resident packed
// fp16 h (pkX/pkY), readlane broadcast, 16 indep. fdot2 chains,
// double-buffered partial exchange, ONE barrier/step, redundant LN tail.

#define BB     128
#define TT     2048
#define DIN    16
#define HH     256
#define NAPP   10
#define NT     512
#define NG     2
#define DT_STEP 0.1f
#define LN_EPS_C 1e-5f
#define LOG2E2  2.8853900817779268f   // 2*log2(e)

typedef _Float16 half2_t __attribute__((ext_vector_type(2)));

__device__ __forceinline__ unsigned pkrtz_u32(float a, float b) {
    return __builtin_bit_cast(unsigned, __builtin_amdgcn_cvt_pkrtz(a, b));
}

template<int CTRL>
__device__ __forceinline__ float dpp_mov0(float x) {
    return __builtin_bit_cast(float,
        __builtin_amdgcn_update_dpp(0, __builtin_bit_cast(int, x), CTRL, 0xF, 0xF, true));
}

// After this, lane 63 holds the wave-wide sums of s1 and s2. (HW-verified r3-r13.)
__device__ __forceinline__ void wave_reduce2(float& s1, float& s2) {
    s1 += dpp_mov0<0x111>(s1); s2 += dpp_mov0<0x111>(s2);  // row_shr:1
    s1 += dpp_mov0<0x112>(s1); s2 += dpp_mov0<0x112>(s2);  // row_shr:2
    s1 += dpp_mov0<0x114>(s1); s2 += dpp_mov0<0x114>(s2);  // row_shr:4
    s1 += dpp_mov0<0x118>(s1); s2 += dpp_mov0<0x118>(s2);  // row_shr:8
    s1 += dpp_mov0<0x142>(s1); s2 += dpp_mov0<0x142>(s2);  // row_bcast:15
    s1 += dpp_mov0<0x143>(s1); s2 += dpp_mov0<0x143>(s2);  // row_bcast:31
}

__device__ __forceinline__ half2_t as_h2(int v) { return __builtin_bit_cast(half2_t, v); }
__device__ __forceinline__ float rl63(float v) {
    return __builtin_bit_cast(float,
        __builtin_amdgcn_readlane(__builtin_bit_cast(int, v), 63));
}
__device__ __forceinline__ float softplus_f(float v) {
    return (v > 20.f) ? v : log1pf(__expf(v));
}
__device__ __forceinline__ float exp2_fast(float v) {
    float r;
    asm("v_exp_f32 %0, %1" : "=v"(r) : "v"(v));   // D = 2^S0
    return r;
}

__global__ __launch_bounds__(NT)
__attribute__((amdgpu_waves_per_eu(2, 2)))
void liquid_scan_kernel(const float* __restrict__ x,
                        const float* __restrict__ W_in,
                        const float* __restrict__ b_in,
                        const float* __restrict__ tau_param,
                        const float* __restrict__ W_rec,
                        const float* __restrict__ g_intra,
                        const float* __restrict__ b_intra,
                        const float* __restrict__ g_norm,
                        const float* __restrict__ b_norm,
                        const float* __restrict__ W_head,
                        const float* __restrict__ b_head,
                        float* __restrict__ out)
{
    const int tid  = threadIdx.x;
    const int g    = tid >> 8;          // batch group 0/1 (wave-uniform)
    const int t4   = tid & 255;         // index within group
    const int lane = tid & 63;
    const int kq   = (tid >> 6) & 3;    // wave-within-group == k-quarter
    const int j0   = lane * 4;          // this lane's 4 output columns
    const int batch = blockIdx.x * NG + g;

    __shared__ __align__(16) unsigned x16[NG][TT * DIN / 2];  // fp16 pairs, 128 KB
    __shared__ __align__(16) float    part[2][NG][4][HH];     // 16 KB, double-buffered

    // ---- stage both batches' x into LDS as fp16 pairs (coalesced float2) ----
    {
        const int total = NG * (TT * DIN / 2);
        for (int i = tid; i < total; i += NT) {
            const int gg  = i >> 14;          // / 16384
            const int off = i & 16383;
            const float2 v =
                ((const float2*)(x + (size_t)(blockIdx.x * NG + gg) * TT * DIN))[off];
            x16[gg][off] = pkrtz_u32(v.x, v.y);
        }
    }

    // ---- packed recurrent weights: w2[c][p] = (W[64kq+2p][j0+c], W[64kq+2p+1][j0+c])
    half2_t w2[4][32];
    #pragma unroll
    for (int p = 0; p < 32; ++p) {
        const float* r0 = W_rec + (size_t)(64 * kq + 2 * p) * HH + j0;
        const float* r1 = r0 + HH;
        #pragma unroll
        for (int c = 0; c < 4; ++c) {
            half2_t t2; t2.x = (_Float16)r0[c]; t2.y = (_Float16)r1[c];
            w2[c][p] = t2;
        }
    }

    // input-proj weights (fp16 pairs): this wave covers input dims [4kq, 4kq+4)
    half2_t win2[4][2];
    #pragma unroll
    for (int c = 0; c < 4; ++c) {
        const float* wr = W_in + (size_t)(j0 + c) * DIN + 4 * kq;
        win2[c][0] = as_h2((int)pkrtz_u32(wr[0], wr[1]));
        win2[c][1] = as_h2((int)pkrtz_u32(wr[2], wr[3]));
    }

    // ---- per-lane IN-LOOP params (gn/bn loaded after the loop; bi folded
    //      into wave 0's partial each step -- kept in a reg only on wave 0)
    float bi_[4] = {0.f, 0.f, 0.f, 0.f};
    if (kq == 0) {
        const float4 v0 = *(const float4*)(b_in + j0);
        bi_[0] = v0.x; bi_[1] = v0.y; bi_[2] = v0.z; bi_[3] = v0.w;
    }
    float gi2_[4], bbi2_[4], dec_[4];
    {
        const float4 v1 = *(const float4*)(g_intra   + j0);
        const float4 v2 = *(const float4*)(b_intra   + j0);
        const float4 v3 = *(const float4*)(tau_param + j0);
        gi2_[0] = v1.x * LOG2E2; gi2_[1] = v1.y * LOG2E2;
        gi2_[2] = v1.z * LOG2E2; gi2_[3] = v1.w * LOG2E2;
        bbi2_[0] = v2.x * LOG2E2; bbi2_[1] = v2.y * LOG2E2;
        bbi2_[2] = v2.z * LOG2E2; bbi2_[3] = v2.w * LOG2E2;
        dec_[0] = 1.f - DT_STEP / softplus_f(v3.x);
        dec_[1] = 1.f - DT_STEP / softplus_f(v3.y);
        dec_[2] = 1.f - DT_STEP / softplus_f(v3.z);
        dec_[3] = 1.f - DT_STEP / softplus_f(v3.w);
    }

    float hj[4] = {0.f, 0.f, 0.f, 0.f};
    int pkX = 0, pkY = 0;   // packed fp16 pairs (h[4l],h[4l+1]) and (h[4l+2],h[4l+3])
    const int rlbase = 16 * kq;          // wave-uniform readlane base
    const int o1 = (kq + 1) & 3, o2 = (kq + 2) & 3, o3 = (kq + 3) & 3;

    __syncthreads();   // x staged

    #pragma unroll 1
    for (int t = 0; t < TT; ++t) {
        // broadcast x pairs for this wave's 4 input dims (same addr all lanes)
        const uint2 xsp = *(const uint2*)&x16[g][t * (DIN / 2) + 2 * kq];

        // ---- dot: 8 groups of {4 readlane -> 16 fdot2}; 16 indep. acc chains
        float acc[4][4];
        #pragma unroll
        for (int c = 0; c < 4; ++c) {
            #pragma unroll
            for (int i = 0; i < 4; ++i) acc[c][i] = 0.f;
        }
        #pragma unroll
        for (int gg = 0; gg < 8; ++gg) {
            const int r0 = __builtin_amdgcn_readlane(pkX, rlbase + 2 * gg);
            const int r1 = __builtin_amdgcn_readlane(pkY, rlbase + 2 * gg);
            const int r2 = __builtin_amdgcn_readlane(pkX, rlbase + 2 * gg + 1);
            const int r3 = __builtin_amdgcn_readlane(pkY, rlbase + 2 * gg + 1);
            #pragma unroll
            for (int c = 0; c < 4; ++c)
                acc[c][0] = __builtin_amdgcn_fdot2(as_h2(r0), w2[c][4 * gg + 0], acc[c][0], false);
            #pragma unroll
            for (int c = 0; c < 4; ++c)
                acc[c][1] = __builtin_amdgcn_fdot2(as_h2(r1), w2[c][4 * gg + 1], acc[c][1], false);
            #pragma unroll
            for (int c = 0; c < 4; ++c)
                acc[c][2] = __builtin_amdgcn_fdot2(as_h2(r2), w2[c][4 * gg + 2], acc[c][2], false);
            #pragma unroll
            for (int c = 0; c < 4; ++c)
                acc[c][3] = __builtin_amdgcn_fdot2(as_h2(r3), w2[c][4 * gg + 3], acc[c][3], false);
        }
        // ---- input projection: 2 fdot2 per column (fp16 x, fp16 W_in)
        #pragma unroll
        for (int c = 0; c < 4; ++c) {
            acc[c][0] = __builtin_amdgcn_fdot2(as_h2((int)xsp.x), win2[c][0], acc[c][0], false);
            acc[c][1] = __builtin_amdgcn_fdot2(as_h2((int)xsp.y), win2[c][1], acc[c][1], false);
        }
        float a[4];
        #pragma unroll
        for (int c = 0; c < 4; ++c)
            a[c] = (acc[c][0] + acc[c][1]) + (acc[c][2] + acc[c][3]);
        if (kq == 0) {       // fold bias into wave 0's partial (and own a)
            #pragma unroll
            for (int c = 0; c < 4; ++c) a[c] += bi_[c];
        }

        ((float4*)part[t & 1][g][kq])[lane] = make_float4(a[0], a[1], a[2], a[3]);
        __syncthreads();   // the ONLY barrier per step (both groups, symmetric)

        const float4 p1 = ((const float4*)part[t & 1][g][o1])[lane];
        const float4 p2 = ((const float4*)part[t & 1][g][o2])[lane];
        const float4 p3 = ((const float4*)part[t & 1][g][o3])[lane];
        float u[4];
        u[0] = (a[0] + p1.x) + (p2.x + p3.x);
        u[1] = (a[1] + p1.y) + (p2.y + p3.y);
        u[2] = (a[2] + p1.z) + (p2.z + p3.z);
        u[3] = (a[3] + p1.w) + (p2.w + p3.w);

        float s1 = (u[0] + u[1]) + (u[2] + u[3]);
        float s2 = (u[0] * u[0] + u[1] * u[1]) + (u[2] * u[2] + u[3] * u[3]);
        wave_reduce2(s1, s2);
        const float S1 = rl63(s1);
        const float S2 = rl63(s2);
        const float mu  = S1 * (1.f / HH);
        const float var = S2 * (1.f / HH) - mu * mu;
        const float rs  = __builtin_amdgcn_rsqf(var + LN_EPS_C);
        #pragma unroll
        for (int c = 0; c < 4; ++c) {
            // tanh(xn) with 2*log2e pre-folded: e = 2^((u-mu)*rs*gi2 + bbi2)
            const float xn2 = fmaf((u[c] - mu) * rs, gi2_[c], bbi2_[c]);
            const float e   = exp2_fast(xn2);
            const float r   = __builtin_amdgcn_rcpf(e + 1.f);   // rcp(inf)=0, rcp(1)=1
            const float fdt = fmaf(-2.f * DT_STEP, r, DT_STEP);
            const float v   = fmaf(hj[c], dec_[c], fdt);
            hj[c] = __builtin_amdgcn_fmed3f(v, -10.f, 10.f);
        }
        pkX = (int)pkrtz_u32(hj[0], hj[1]);
        pkY = (int)pkrtz_u32(hj[2], hj[3]);
    }

    // ---- final LayerNorm (g_norm, b_norm loaded HERE) + head (per group, wave 0)
    if (kq == 0) {
        const float4 v4 = *(const float4*)(g_norm + j0);
        const float4 v5 = *(const float4*)(b_norm + j0);
        float s1 = (hj[0] + hj[1]) + (hj[2] + hj[3]);
        float s2 = (hj[0] * hj[0] + hj[1] * hj[1]) + (hj[2] * hj[2] + hj[3] * hj[3]);
        wave_reduce2(s1, s2);
        const float S1 = rl63(s1);
        const float S2 = rl63(s2);
        const float mu  = S1 * (1.f / HH);
        const float var = S2 * (1.f / HH) - mu * mu;
        const float rs  = rsqrtf(var + LN_EPS_C);
        float4 ho;
        ho.x = (hj[0] - mu) * rs * v4.x + v5.x;
        ho.y = (hj[1] - mu) * rs * v4.y + v5.y;
        ho.z = (hj[2] - mu) * rs * v4.z + v5.z;
        ho.w = (hj[3] - mu) * rs * v4.w + v5.w;
        ((float4*)part[0][g][0])[lane] = ho;
    }
    __syncthreads();
    if (t4 < NAPP) {
        float o = b_head[t4];
        for (int jj = 0; jj < HH; ++jj)
            o = fmaf(part[0][g][0][jj], W_head[jj * NAPP + t4], o);
        out[(size_t)batch * NAPP + t4] = o;
    }
}

extern "C" void kernel_launch(void* const* d_in, const int* in_sizes, int n_in,
                              void* d_out, int out_size, void* d_ws, size_t ws_size,
                              hipStream_t stream) {
    const float* x       = (const float*)d_in[0];
    const float* W_in    = (const float*)d_in[1];
    const float* b_in    = (const float*)d_in[2];
    const float* tau     = (const float*)d_in[3];
    const float* W_rec   = (const float*)d_in[4];
    const float* g_intra = (const float*)d_in[5];
    const float* b_intra = (const float*)d_in[6];
    const float* g_norm  = (const float*)d_in[7];
    const float* b_norm  = (const float*)d_in[8];
    const float* W_head  = (const float*)d_in[9];
    const float* b_head  = (const float*)d_in[10];
    float* out = (float*)d_out;

    hipLaunchKernelGGL(liquid_scan_kernel, dim3(BB / NG), dim3(NT), 0, stream,
                       x, W_in, b_in, tau, W_rec, g_intra, b_intra,
                       g_norm, b_norm, W_head, b_head, out);
}

// Round 15
// 2529.528 us; speedup vs baseline: 1.0878x; 1.0878x over previous
//
#include <hip/hip_runtime.h>

// Liquid-network scan, r15: TWO-wave blocks (128 thr), one batch per block.
// Rationale: r8's 1150 cyc/step stall is cross-wave choreography latency
// (write->barrier->read round trip, max-of-4 arrival skew, 3-partial
// combine, serial dependent tail). Halving the waves to 2 collapses the
// exchange to ONE partner (1 b128 read, max-of-2 skew) at the cost of +420
// issue cyc in the dot (issue is only ~38% of step time). Wave w owns
// k in [128w, 128w+128) (pairs 64w..64w+64) for each lane's 4 columns
// (j0 = 4*lane): 64 readlane + 256 fdot2 in 16 groups, 16 indep chains.
// x staged as fp16 pairs (64 KB, r12-proven); input proj via 4 fdot2/col.
// ONE barrier/step; redundant LN tail on both waves; h in packed-fp16 regs.

#define BB     128
#define TT     2048
#define DIN    16
#define HH     256
#define NAPP   10
#define NT     128
#define DT_STEP 0.1f
#define LN_EPS_C 1e-5f
#define LOG2E2  2.8853900817779268f   // 2*log2(e)

typedef _Float16 half2_t __attribute__((ext_vector_type(2)));

__device__ __forceinline__ unsigned pkrtz_u32(float a, float b) {
    return __builtin_bit_cast(unsigned, __builtin_amdgcn_cvt_pkrtz(a, b));
}

template<int CTRL>
__device__ __forceinline__ float dpp_mov0(float x) {
    return __builtin_bit_cast(float,
        __builtin_amdgcn_update_dpp(0, __builtin_bit_cast(int, x), CTRL, 0xF, 0xF, true));
}

// After this, lane 63 holds the wave-wide sums of s1 and s2. (HW-verified r3-r14.)
__device__ __forceinline__ void wave_reduce2(float& s1, float& s2) {
    s1 += dpp_mov0<0x111>(s1); s2 += dpp_mov0<0x111>(s2);  // row_shr:1
    s1 += dpp_mov0<0x112>(s1); s2 += dpp_mov0<0x112>(s2);  // row_shr:2
    s1 += dpp_mov0<0x114>(s1); s2 += dpp_mov0<0x114>(s2);  // row_shr:4
    s1 += dpp_mov0<0x118>(s1); s2 += dpp_mov0<0x118>(s2);  // row_shr:8
    s1 += dpp_mov0<0x142>(s1); s2 += dpp_mov0<0x142>(s2);  // row_bcast:15
    s1 += dpp_mov0<0x143>(s1); s2 += dpp_mov0<0x143>(s2);  // row_bcast:31
}

__device__ __forceinline__ half2_t as_h2(int v) { return __builtin_bit_cast(half2_t, v); }
__device__ __forceinline__ float rl63(float v) {
    return __builtin_bit_cast(float,
        __builtin_amdgcn_readlane(__builtin_bit_cast(int, v), 63));
}
__device__ __forceinline__ float softplus_f(float v) {
    return (v > 20.f) ? v : log1pf(__expf(v));
}
__device__ __forceinline__ float exp2_fast(float v) {
    float r;
    asm("v_exp_f32 %0, %1" : "=v"(r) : "v"(v));   // D = 2^S0
    return r;
}

__global__ __launch_bounds__(NT, 1)
void liquid_scan_kernel(const float* __restrict__ x,
                        const float* __restrict__ W_in,
                        const float* __restrict__ b_in,
                        const float* __restrict__ tau_param,
                        const float* __restrict__ W_rec,
                        const float* __restrict__ g_intra,
                        const float* __restrict__ b_intra,
                        const float* __restrict__ g_norm,
                        const float* __restrict__ b_norm,
                        const float* __restrict__ W_head,
                        const float* __restrict__ b_head,
                        float* __restrict__ out)
{
    const int tid  = threadIdx.x;
    const int b    = blockIdx.x;
    const int lane = tid & 63;
    const int w    = tid >> 6;          // wave id 0/1 == k-half (wave-uniform)
    const int j0   = lane * 4;          // this lane's 4 output columns

    __shared__ __align__(16) unsigned x16[TT * DIN / 2];  // fp16 pairs, 64 KB
    __shared__ __align__(16) float    part[2][2][HH];     // 4 KB, double-buffered

    // ---- stage x as fp16 pairs (coalesced float2; once) ----
    {
        const float2* xg = (const float2*)(x + (size_t)b * TT * DIN);
        for (int i = tid; i < TT * DIN / 2; i += NT) {
            const float2 v = xg[i];
            x16[i] = pkrtz_u32(v.x, v.y);
        }
    }

    // ---- packed recurrent weights: w2[c][p] = (W[128w+2p][j0+c], W[128w+2p+1][j0+c])
    half2_t w2[4][64];
    #pragma unroll
    for (int p = 0; p < 64; ++p) {
        const float* r0 = W_rec + (size_t)(128 * w + 2 * p) * HH + j0;
        const float* r1 = r0 + HH;
        #pragma unroll
        for (int c = 0; c < 4; ++c) {
            half2_t t2; t2.x = (_Float16)r0[c]; t2.y = (_Float16)r1[c];
            w2[c][p] = t2;
        }
    }

    // input-proj weights (fp16 pairs): this wave covers input dims [8w, 8w+8)
    half2_t win2[4][4];
    #pragma unroll
    for (int c = 0; c < 4; ++c) {
        #pragma unroll
        for (int q = 0; q < 4; ++q) {
            const float* wr = W_in + (size_t)(j0 + c) * DIN + 8 * w + 2 * q;
            win2[c][q] = as_h2((int)pkrtz_u32(wr[0], wr[1]));
        }
    }

    // ---- per-lane in-loop params (gn/bn loaded after the loop) ----
    float bi_[4] = {0.f, 0.f, 0.f, 0.f};
    if (w == 0) {
        const float4 v0 = *(const float4*)(b_in + j0);
        bi_[0] = v0.x; bi_[1] = v0.y; bi_[2] = v0.z; bi_[3] = v0.w;
    }
    float gi2_[4], bbi2_[4], dec_[4];
    {
        const float4 v1 = *(const float4*)(g_intra   + j0);
        const float4 v2 = *(const float4*)(b_intra   + j0);
        const float4 v3 = *(const float4*)(tau_param + j0);
        gi2_[0] = v1.x * LOG2E2; gi2_[1] = v1.y * LOG2E2;
        gi2_[2] = v1.z * LOG2E2; gi2_[3] = v1.w * LOG2E2;
        bbi2_[0] = v2.x * LOG2E2; bbi2_[1] = v2.y * LOG2E2;
        bbi2_[2] = v2.z * LOG2E2; bbi2_[3] = v2.w * LOG2E2;
        dec_[0] = 1.f - DT_STEP / softplus_f(v3.x);
        dec_[1] = 1.f - DT_STEP / softplus_f(v3.y);
        dec_[2] = 1.f - DT_STEP / softplus_f(v3.z);
        dec_[3] = 1.f - DT_STEP / softplus_f(v3.w);
    }

    float hj[4] = {0.f, 0.f, 0.f, 0.f};
    int pkX = 0, pkY = 0;   // packed fp16 pairs (h[4l],h[4l+1]) and (h[4l+2],h[4l+3])
    const int rlbase = 32 * w;          // wave-uniform readlane base
    const int ow = w ^ 1;

    __syncthreads();   // x staged

    #pragma unroll 1
    for (int t = 0; t < TT; ++t) {
        // broadcast x pairs for this wave's 8 input dims (same addr all lanes)
        const uint4 xsp = *(const uint4*)&x16[t * (DIN / 2) + 4 * w];

        // ---- dot: 16 groups of {4 readlane -> 16 fdot2}; 16 indep. acc chains
        float acc[4][4];
        #pragma unroll
        for (int c = 0; c < 4; ++c) {
            #pragma unroll
            for (int i = 0; i < 4; ++i) acc[c][i] = 0.f;
        }
        #pragma unroll
        for (int gg = 0; gg < 16; ++gg) {
            const int r0 = __builtin_amdgcn_readlane(pkX, rlbase + 2 * gg);
            const int r1 = __builtin_amdgcn_readlane(pkY, rlbase + 2 * gg);
            const int r2 = __builtin_amdgcn_readlane(pkX, rlbase + 2 * gg + 1);
            const int r3 = __builtin_amdgcn_readlane(pkY, rlbase + 2 * gg + 1);
            #pragma unroll
            for (int c = 0; c < 4; ++c)
                acc[c][0] = __builtin_amdgcn_fdot2(as_h2(r0), w2[c][4 * gg + 0], acc[c][0], false);
            #pragma unroll
            for (int c = 0; c < 4; ++c)
                acc[c][1] = __builtin_amdgcn_fdot2(as_h2(r1), w2[c][4 * gg + 1], acc[c][1], false);
            #pragma unroll
            for (int c = 0; c < 4; ++c)
                acc[c][2] = __builtin_amdgcn_fdot2(as_h2(r2), w2[c][4 * gg + 2], acc[c][2], false);
            #pragma unroll
            for (int c = 0; c < 4; ++c)
                acc[c][3] = __builtin_amdgcn_fdot2(as_h2(r3), w2[c][4 * gg + 3], acc[c][3], false);
        }
        // ---- input projection: 4 fdot2 per column (fp16 x, fp16 W_in), 1/chain
        #pragma unroll
        for (int c = 0; c < 4; ++c) {
            acc[c][0] = __builtin_amdgcn_fdot2(as_h2((int)xsp.x), win2[c][0], acc[c][0], false);
            acc[c][1] = __builtin_amdgcn_fdot2(as_h2((int)xsp.y), win2[c][1], acc[c][1], false);
            acc[c][2] = __builtin_amdgcn_fdot2(as_h2((int)xsp.z), win2[c][2], acc[c][2], false);
            acc[c][3] = __builtin_amdgcn_fdot2(as_h2((int)xsp.w), win2[c][3], acc[c][3], false);
        }
        float a[4];
        #pragma unroll
        for (int c = 0; c < 4; ++c)
            a[c] = (acc[c][0] + acc[c][1]) + (acc[c][2] + acc[c][3]);
        if (w == 0) {       // fold bias into wave 0's partial
            #pragma unroll
            for (int c = 0; c < 4; ++c) a[c] += bi_[c];
        }

        ((float4*)part[t & 1][w])[lane] = make_float4(a[0], a[1], a[2], a[3]);
        __syncthreads();   // the ONLY barrier per step (2 waves, min skew)

        const float4 p1 = ((const float4*)part[t & 1][ow])[lane];
        float u[4];
        u[0] = a[0] + p1.x;
        u[1] = a[1] + p1.y;
        u[2] = a[2] + p1.z;
        u[3] = a[3] + p1.w;

        float s1 = (u[0] + u[1]) + (u[2] + u[3]);
        float s2 = (u[0] * u[0] + u[1] * u[1]) + (u[2] * u[2] + u[3] * u[3]);
        wave_reduce2(s1, s2);
        const float S1 = rl63(s1);
        const float S2 = rl63(s2);
        const float mu  = S1 * (1.f / HH);
        const float var = S2 * (1.f / HH) - mu * mu;
        const float rs  = __builtin_amdgcn_rsqf(var + LN_EPS_C);
        #pragma unroll
        for (int c = 0; c < 4; ++c) {
            // tanh(xn) with 2*log2e pre-folded: e = 2^((u-mu)*rs*gi2 + bbi2)
            const float xn2 = fmaf((u[c] - mu) * rs, gi2_[c], bbi2_[c]);
            const float e   = exp2_fast(xn2);
            const float r   = __builtin_amdgcn_rcpf(e + 1.f);   // rcp(inf)=0, rcp(1)=1
            const float fdt = fmaf(-2.f * DT_STEP, r, DT_STEP);
            const float v   = fmaf(hj[c], dec_[c], fdt);
            hj[c] = __builtin_amdgcn_fmed3f(v, -10.f, 10.f);
        }
        pkX = (int)pkrtz_u32(hj[0], hj[1]);
        pkY = (int)pkrtz_u32(hj[2], hj[3]);
    }

    // ---- final LayerNorm (g_norm, b_norm loaded HERE) + head (wave 0) ----
    if (w == 0) {
        const float4 v4 = *(const float4*)(g_norm + j0);
        const float4 v5 = *(const float4*)(b_norm + j0);
        float s1 = (hj[0] + hj[1]) + (hj[2] + hj[3]);
        float s2 = (hj[0] * hj[0] + hj[1] * hj[1]) + (hj[2] * hj[2] + hj[3] * hj[3]);
        wave_reduce2(s1, s2);
        const float S1 = rl63(s1);
        const float S2 = rl63(s2);
        const float mu  = S1 * (1.f / HH);
        const float var = S2 * (1.f / HH) - mu * mu;
        const float rs  = rsqrtf(var + LN_EPS_C);
        float4 ho;
        ho.x = (hj[0] - mu) * rs * v4.x + v5.x;
        ho.y = (hj[1] - mu) * rs * v4.y + v5.y;
        ho.z = (hj[2] - mu) * rs * v4.z + v5.z;
        ho.w = (hj[3] - mu) * rs * v4.w + v5.w;
        ((float4*)part[0][0])[lane] = ho;
    }
    __syncthreads();
    if (tid < NAPP) {
        float o = b_head[tid];
        for (int jj = 0; jj < HH; ++jj)
            o = fmaf(part[0][0][jj], W_head[jj * NAPP + tid], o);
        out[(size_t)b * NAPP + tid] = o;
    }
}

extern "C" void kernel_launch(void* const* d_in, const int* in_sizes, int n_in,
                              void* d_out, int out_size, void* d_ws, size_t ws_size,
                              hipStream_t stream) {
    const float* x       = (const float*)d_in[0];
    const float* W_in    = (const float*)d_in[1];
    const float* b_in    = (const float*)d_in[2];
    const float* tau     = (const float*)d_in[3];
    const float* W_rec   = (const float*)d_in[4];
    const float* g_intra = (const float*)d_in[5];
    const float* b_intra = (const float*)d_in[6];
    const float* g_norm  = (const float*)d_in[7];
    const float* b_norm  = (const float*)d_in[8];
    const float* W_head  = (const float*)d_in[9];
    const float* b_head  = (const float*)d_in[10];
    float* out = (float*)d_out;

    hipLaunchKernelGGL(liquid_scan_kernel, dim3(BB), dim3(NT), 0, stream,
                       x, W_in, b_in, tau, W_rec, g_intra, b_intra,
                       g_norm, b_norm, W_head, b_head, out);
}